// Round 6
// baseline (162.083 us; speedup 1.0000x reference)
//
#include <hip/hip_runtime.h>

#define HH 256
#define WW 256
#define HW (HH * WW)
#define NB 8
#define NPTS 65536
#define EPSW 1e-5f
#define BIGBITS 0x501502F9u   // __float_as_uint(1e10f)

#define TPB 64                // tiles per image (8x8 of 32x32)
#define NBLK (NB * TPB)       // 512 blocks == exactly 2/CU co-resident
#define BCA 48                // phase-A LDS bucket cap (mean 27.5, +3.9 sigma; fallback below)
#define TCAP 2048             // per-tile list cap (mean ~1764 — r0-accepted risk)
#define VC 384                // visible list cap (mean ~92)
#define SDS 36                // accum stride: (36r+c)%32 -> <=2-way on 8x8 = free
#define ZRW 42                // z-image cols: [bj-5, bj+36]
#define ZRH 42
#define ZMW 38                // zmin cols: [bj-3, bj+34]
#define ZMH 38

// Phase A (binning) and phase B (render) never live simultaneously -> union.
union SM {
    struct {                                   // 49.7 KB
        float4 bins[TPB * BCA];
        unsigned int cnt[TPB];
        unsigned int sbase[TPB];
    } a;
    struct {                                   // 65.8 KB (incl. staged)
        unsigned int zraw[ZRH * ZRW];
        float hmin[ZRH * ZMW];
        float zminb[ZMH * ZMW];
        float sdep[32 * SDS];
        float swei[32 * SDS];
        float vx[VC], vy[VC], vz[VC];
        float4 staged[TCAP];
        int vcnt;
    } b;
};

// ONE dispatch: bin -> manual grid barrier (per-image arrival counter) -> render.
// 512 blocks x 1024 thr; LDS 65.8KB + VGPR<=64 guarantee 2 blocks/CU, so all
// 512 blocks are resident from t=0 and the barrier cannot deadlock.
__global__ void __launch_bounds__(1024, 8) render_fused(
        const float* __restrict__ pts, const float* __restrict__ thr_p,
        float* __restrict__ vis, float* __restrict__ depth, float* __restrict__ weight,
        unsigned int* __restrict__ tileCnt, unsigned int* __restrict__ imgDone,
        float4* __restrict__ lists) {
    __shared__ SM sm;
    int tid = threadIdx.x;
    int blk = blockIdx.x;
    int b   = blk >> 6;                        // image: blocks [64b, 64b+63]
    float thr = *thr_p;

    // ---- Phase A: bin this block's 1024 points into per-tile contiguous lists ----
    if (tid < TPB) sm.a.cnt[tid] = 0u;
    __syncthreads();
    {
        int i = blk * 1024 + tid;              // global point id
        float x = pts[i * 3 + 0];
        float y = pts[i * 3 + 1];
        float z = pts[i * 3 + 2];
        int px = __float2int_rn(x);            // round-half-even = jnp.round
        int py = __float2int_rn(y);
        if (px >= 0 && px < WW && py >= 0 && py < HH) {
            int tx0 = max((px - 5) >> 5, 0), tx1 = min((px + 5) >> 5, 7);
            int ty0 = max((py - 5) >> 5, 0), ty1 = min((py + 5) >> 5, 7);
            float4 e = make_float4(x, y, z, __uint_as_float((unsigned int)i));
            for (int ty = ty0; ty <= ty1; ++ty)
                for (int tx = tx0; tx <= tx1; ++tx) {
                    int bin = ty * 8 + tx;
                    unsigned int pos = atomicAdd(&sm.a.cnt[bin], 1u);
                    if (pos < BCA) {
                        sm.a.bins[bin * BCA + pos] = e;
                    } else {                   // rare overflow: direct global append
                        unsigned int dst = atomicAdd(&tileCnt[(b << 6) + bin], 1u);
                        if (dst < TCAP) lists[(size_t)((b << 6) + bin) * TCAP + dst] = e;
                    }
                }
        } else {
            vis[i] = 0.0f;                     // dataset: never taken
        }
        __syncthreads();

        // reserve contiguous per-tile ranges (1 atomicAdd per non-empty bin)
        int bin = tid >> 4, lane = tid & 15;   // 16 threads per bin
        unsigned int c = sm.a.cnt[bin]; if (c > BCA) c = BCA;
        if (lane == 0)
            sm.a.sbase[bin] = c ? atomicAdd(&tileCnt[(b << 6) + bin], c) : 0u;
        __syncthreads();
        unsigned int base = sm.a.sbase[bin];
        size_t tb = (size_t)((b << 6) + bin) * TCAP;
        for (unsigned int p = lane; p < c; p += 16) {   // coalesced 256B bursts
            unsigned int dst = base + p;
            if (dst < TCAP) lists[tb + dst] = sm.a.bins[bin * BCA + p];
        }
    }
    __syncthreads();                           // all phase-A LDS reads done (union safe)
    if (tid == 0) {
        __threadfence();                       // agent-scope release of lists/tileCnt
        __hip_atomic_fetch_add(&imgDone[b], 1u, __ATOMIC_RELEASE, __HIP_MEMORY_SCOPE_AGENT);
    }

    // ---- Phase B init (overlaps other blocks' phase A; LDS only) ----
    if (tid == 0) sm.b.vcnt = 0;
    for (int t = tid; t < ZRH * ZRW; t += 1024) sm.b.zraw[t] = BIGBITS;
    for (int t = tid; t < 32 * SDS; t += 1024) { sm.b.sdep[t] = 0.0f; sm.b.swei[t] = 0.0f; }

    // ---- Grid barrier: wait for this image's 64 producers ----
    if (tid == 0) {
        while (__hip_atomic_load(&imgDone[b], __ATOMIC_ACQUIRE, __HIP_MEMORY_SCOPE_AGENT) < 64u)
            __builtin_amdgcn_s_sleep(2);
    }
    __syncthreads();   // S1: lists visible + LDS init done

    // ---- Phase B: r0-proven tile render; block == tile ----
    int tr = blk & 63;
    int ty = tr >> 3, tx = tr & 7;
    int bi = ty * 32, bj = tx * 32;

    int n = (int)__hip_atomic_load(&tileCnt[blk], __ATOMIC_RELAXED, __HIP_MEMORY_SCOPE_AGENT);
    if (n > TCAP) n = TCAP;
    size_t tb = (size_t)blk * TCAP;

    // P2: stage list into LDS + own-pixel z-min (contiguous coalesced reads)
    for (int g = tid; g < n; g += 1024) {
        float4 e = lists[tb + g];
        sm.b.staged[g] = e;
        int px = __float2int_rn(e.x);
        int py = __float2int_rn(e.y);
        int r = py - bi + 5, c = px - bj + 5;            // in [0,41] by binning
        atomicMin(&sm.b.zraw[r * ZRW + c], __float_as_uint(e.z));  // uint==float order (z>0)
    }
    __syncthreads();   // S2

    // P3: horizontal 5-min
    for (int t = tid; t < ZRH * ZMW; t += 1024) {
        int r = t / ZMW, c = t - r * ZMW;
        const unsigned int* p = &sm.b.zraw[r * ZRW + c];
        float m = fminf(__uint_as_float(p[0]), __uint_as_float(p[1]));
        m = fminf(m, fminf(__uint_as_float(p[2]), __uint_as_float(p[3])));
        sm.b.hmin[t] = fminf(m, __uint_as_float(p[4]));
    }
    __syncthreads();   // S3

    // P4: vertical 5-min -> zminb == reference z-buffer on the +-3 window
    for (int t = tid; t < ZMH * ZMW; t += 1024) {
        int c = t % ZMW;
        const float* p = &sm.b.hmin[(t / ZMW) * ZMW + c];
        sm.b.zminb[t] = fminf(fminf(fminf(p[0], p[ZMW]), fminf(p[2 * ZMW], p[3 * ZMW])), p[4 * ZMW]);
    }
    __syncthreads();   // S4

    // P5: visibility scan over staged, home vis write, compact visible list
    for (int g = tid; g < n; g += 1024) {
        float4 p = sm.b.staged[g];
        int px = __float2int_rn(p.x);
        int py = __float2int_rn(p.y);
        if (px < bj - 3 || px > bj + 34 || py < bi - 3 || py > bi + 34)
            continue;                          // zmin-only fringe entry
        float zmin = sm.b.zminb[(py - bi + 3) * ZMW + (px - bj + 3)];
        bool visible = (p.z <= zmin + thr);
        if (((px >> 5) == tx) && ((py >> 5) == ty))      // home tile writes vis once
            vis[__float_as_uint(p.w)] = visible ? 1.0f : 0.0f;
        if (visible) {
            int vp = atomicAdd(&sm.b.vcnt, 1);
            if (vp < VC) { sm.b.vx[vp] = p.x; sm.b.vy[vp] = p.y; sm.b.vz[vp] = p.z; }
        }
    }
    __syncthreads();   // S5

    // P6: tap-parallel splat; (e,tap) tracked incrementally (step +1024 = +20e +44t)
    int nv = sm.b.vcnt; if (nv > VC) nv = VC;
    int total3 = nv * 49;
    int e = (int)((unsigned int)tid / 49u);
    int tap = tid - e * 49;
    for (int g = tid; g < total3; g += 1024) {
        int r = ((unsigned int)(tap * 37)) >> 8;         // tap/7, exact for 0..48
        int c = tap - r * 7;
        float x = sm.b.vx[e], y = sm.b.vy[e], z = sm.b.vz[e];
        int px = __float2int_rn(x);
        int py = __float2int_rn(y);
        int ii = py - 3 + r, jj = px - 3 + c;
        int li = ii - bi, lj = jj - bj;
        if (li >= 0 && li < 32 && lj >= 0 && lj < 32) {  // own-tile taps only
            float dy = y - (float)ii, dx = x - (float)jj;
            float w = 1.0f / (dx * dx + dy * dy + EPSW);
            atomicAdd(&sm.b.sdep[li * SDS + lj], w * z);
            atomicAdd(&sm.b.swei[li * SDS + lj], w);
        }
        e += 20; tap += 44;                              // 1024 = 20*49 + 44
        if (tap >= 49) { tap -= 49; e += 1; }
    }
    __syncthreads();   // S6

    // P7: dense coalesced stores (each pixel owned by exactly one tile)
    for (int t = tid; t < 32 * 32; t += 1024) {
        int li = t >> 5, lj = t & 31;
        int g = b * HW + (bi + li) * WW + (bj + lj);
        depth[g]  = sm.b.sdep[li * SDS + lj];
        weight[g] = sm.b.swei[li * SDS + lj];
    }
}

extern "C" void kernel_launch(void* const* d_in, const int* in_sizes, int n_in,
                              void* d_out, int out_size, void* d_ws, size_t ws_size,
                              hipStream_t stream) {
    const float* pts   = (const float*)d_in[0];   // [B, N, 3]
    const float* thr_p = (const float*)d_in[1];   // scalar

    float* depth  = (float*)d_out;                 // [B*H*W]
    float* weight = depth + NB * HW;               // [B*H*W]
    float* vis    = weight + NB * HW;              // [B*N]

    unsigned int* tileCnt = (unsigned int*)d_ws;               // [512]
    unsigned int* imgDone = tileCnt + NBLK;                    // [8]
    float4* lists = (float4*)((char*)d_ws + 4096);             // 512*2048*16 = 16.8 MB

    hipMemsetAsync(d_ws, 0, 4096, stream);        // zero counters (ws is poisoned)
    render_fused<<<NBLK, 1024, 0, stream>>>(pts, thr_p, vis, depth, weight,
                                            tileCnt, imgDone, lists);
}

// Round 7
// 105.924 us; speedup vs baseline: 1.5302x; 1.5302x over previous
//
#include <hip/hip_runtime.h>

#define HH 256
#define WW 256
#define HW (HH * WW)
#define NB 8
#define NPTS 65536
#define EPSW 1e-5f
#define BIGF 1e10f
#define BIGBITS 0x501502F9u       // __float_as_uint(1e10f)

#define PPB 256                   // points per bin block (256 thr x 1)
#define BPI (NPTS / PPB)          // 256 bin blocks (segments) per image
#define TPB 64                    // 32x32 tiles per image (8x8)
#define BCAP 30                   // LDS bucket capacity (lambda ~6.89 with +-5 halo)

#define SDS 36                    // accumulator stride: (36r+c)%32 -> <=2-way on 8x8 = free
#define VCAP 384                  // compacted visible list cap (mean ~92)
#define SEGT 2048                 // staged entries cap (mean ~1764, +6.8 sigma)
#define ZRW 42                    // LDS z-image cols: [base_j-5, base_j+36]
#define ZRH 42
#define ZMW 38                    // zmin cols: [base_j-3, base_j+34]
#define ZMH 38

// ---- Dispatch 1: pure binning — entries are u32 POINT INDICES (4x less traffic) ----
__global__ void __launch_bounds__(256) bin_k(
        const float* __restrict__ pts, float* __restrict__ vis,
        unsigned char* __restrict__ counts, unsigned int* __restrict__ entries) {
    __shared__ unsigned int bins[TPB * BCAP];  // 7.7 KB -> 8 blocks/CU (thread-limited)
    __shared__ unsigned int cnt[TPB];

    if (threadIdx.x < TPB) cnt[threadIdx.x] = 0u;
    __syncthreads();

    int b   = blockIdx.x / BPI;
    int blk = blockIdx.x % BPI;
    int i = blockIdx.x * 256 + threadIdx.x;    // one point per thread (global id)
    float x = pts[i * 3 + 0];
    float y = pts[i * 3 + 1];
    int px = __float2int_rn(x);                // round-half-even = jnp.round
    int py = __float2int_rn(y);
    bool in_img = (px >= 0) && (px < WW) && (py >= 0) && (py < HH);
    if (in_img) {
        int tx0 = max((px - 5) >> 5, 0), tx1 = min((px + 5) >> 5, 7);
        int ty0 = max((py - 5) >> 5, 0), ty1 = min((py + 5) >> 5, 7);
        for (int ty = ty0; ty <= ty1; ++ty)
            for (int tx = tx0; tx <= tx1; ++tx) {
                int bin = ty * 8 + tx;
                unsigned int pos = atomicAdd(&cnt[bin], 1u);
                if (pos < BCAP) bins[bin * BCAP + pos] = (unsigned int)i;
            }
    } else {
        vis[i] = 0.0f;                          // dataset: never taken
    }
    __syncthreads();

    // coalesced u8 counts: counts[b][tile][blk]
    if (threadIdx.x < TPB) {
        unsigned int c = cnt[threadIdx.x];
        if (c > BCAP) c = BCAP;
        counts[(((size_t)b * TPB + threadIdx.x) << 8) | blk] = (unsigned char)c;
    }
    // balanced flush: 4 threads per bin copy exactly cnt indices
    int bin = threadIdx.x >> 2, lane = threadIdx.x & 3;
    unsigned int c = cnt[bin];
    if (c > BCAP) c = BCAP;
    size_t segbase = ((size_t)(b * BPI + blk)) * TPB * BCAP + (size_t)bin * BCAP;
    for (unsigned int p = lane; p < c; p += 4)
        entries[segbase + p] = bins[bin * BCAP + p];
}

// ---- Dispatch 2: per 32x32 tile, 1024 threads — all-LDS z-buffer + scan + splat ----
__global__ void __launch_bounds__(1024) splat_k(
        const unsigned char* __restrict__ counts, const unsigned int* __restrict__ entries,
        const float* __restrict__ pts, const float* __restrict__ thr_p,
        float* __restrict__ vis, float* __restrict__ depth, float* __restrict__ weight) {
    __shared__ unsigned int zraw[ZRH * ZRW];   // 7.1 KB own-pixel min (uint bits)
    __shared__ float hmin[ZRH * ZMW];          // 6.4 KB
    __shared__ float zminb[ZMH * ZMW];         // 5.8 KB
    __shared__ float sdep[32 * SDS];           // 4.6 KB
    __shared__ float swei[32 * SDS];           // 4.6 KB
    __shared__ float vx[VCAP], vy[VCAP], vz[VCAP];  // 4.6 KB
    __shared__ float4 staged[SEGT];            // 32 KB
    __shared__ unsigned int pref[BPI + 1];     // 1 KB
    __shared__ int vcnt;                       // total ~66 KB -> 2 blocks/CU

    int tile = blockIdx.x;
    int b  = tile / TPB, tr = tile % TPB;
    int ty = tr >> 3, tx = tr & 7;
    int base_i = ty * 32, base_j = tx * 32;
    const unsigned char* crow = counts + (((size_t)b * TPB + tr) << 8);
    int tid = threadIdx.x;
    float thr = *thr_p;                        // scalar load, overlaps everything below

    if (tid == 0) { pref[0] = 0; vcnt = 0; }
    // P1: init LDS z-image + accumulators; wave 0: one-phase scan of all 256 counts
    for (int t = tid; t < ZRH * ZRW; t += 1024) zraw[t] = BIGBITS;
    for (int t = tid; t < 32 * SDS; t += 1024) { sdep[t] = 0.0f; swei[t] = 0.0f; }
    if (tid < 64) {                            // wave 0: 4 u8 counts per lane (coalesced u32)
        unsigned int quad = ((const unsigned int*)crow)[tid];
        unsigned int b0 = quad & 0xFFu, b1 = (quad >> 8) & 0xFFu;
        unsigned int b2 = (quad >> 16) & 0xFFu, b3 = quad >> 24;
        unsigned int s4 = b0 + b1 + b2 + b3;
        unsigned int pv = s4;                  // 64-lane inclusive shuffle scan
        #pragma unroll
        for (int d = 1; d < 64; d <<= 1) {
            unsigned int n = (unsigned int)__shfl_up((int)pv, d, 64);
            if (tid >= d) pv += n;
        }
        unsigned int excl = pv - s4;
        pref[4 * tid + 1] = excl + b0;
        pref[4 * tid + 2] = excl + b0 + b1;
        pref[4 * tid + 3] = excl + b0 + b1 + b2;
        pref[4 * tid + 4] = pv;
    }
    __syncthreads();   // S1: zraw, accumulators, pref all ready

    // P2: stage index->xyz (L2-hot pts gather) into LDS + fused own-pixel atomicMin
    {
        int seg = tid >> 2, lane = tid & 3;
        unsigned int s0 = pref[seg];
        unsigned int c = pref[seg + 1] - s0;
        size_t segbase = ((size_t)(b * BPI + seg) * TPB + tr) * BCAP;
        for (unsigned int p = lane; p < c; p += 4) {
            unsigned int idx = entries[segbase + p];
            float x = pts[idx * 3 + 0];        // gather from 768KB L2-hot slice
            float y = pts[idx * 3 + 1];
            float z = pts[idx * 3 + 2];
            unsigned int dst = s0 + p;
            if (dst < SEGT) staged[dst] = make_float4(x, y, z, __uint_as_float(idx));
            int px = __float2int_rn(x);
            int py = __float2int_rn(y);
            int r = py - base_i + 5, cc = px - base_j + 5;   // in [0,41] by binning
            atomicMin(&zraw[r * ZRW + cc], __float_as_uint(z));  // uint==float order (z>0)
        }
    }
    __syncthreads();   // S2

    // P3: horizontal 5-min
    for (int t = tid; t < ZRH * ZMW; t += 1024) {
        int r = t / ZMW, c = t - r * ZMW;
        const unsigned int* p = &zraw[r * ZRW + c];
        float m = fminf(__uint_as_float(p[0]), __uint_as_float(p[1]));
        m = fminf(m, fminf(__uint_as_float(p[2]), __uint_as_float(p[3])));
        hmin[t] = fminf(m, __uint_as_float(p[4]));
    }
    __syncthreads();   // S3

    // P4: vertical 5-min
    for (int t = tid; t < ZMH * ZMW; t += 1024) {
        int c = t % ZMW;
        const float* p = &hmin[(t / ZMW) * ZMW + c];
        zminb[t] = fminf(fminf(fminf(p[0], p[ZMW]), fminf(p[2 * ZMW], p[3 * ZMW])), p[4 * ZMW]);
    }
    __syncthreads();   // S4

    // P5: scan staged entries: patch-intersect filter, visibility, vis write, compact
    int total = (int)pref[BPI];
    if (total > SEGT) total = SEGT;
    for (int g = tid; g < total; g += 1024) {
        float4 p = staged[g];
        float x = p.x, y = p.y, z = p.z;
        int px = __float2int_rn(x);
        int py = __float2int_rn(y);
        if (px < base_j - 3 || px > base_j + 34 || py < base_i - 3 || py > base_i + 34)
            continue;                          // zmin-only fringe entry
        float zmin = zminb[(py - base_i + 3) * ZMW + (px - base_j + 3)];
        bool visible = (z <= zmin + thr);
        if (((px >> 5) == tx) && ((py >> 5) == ty))   // home tile writes vis once
            vis[__float_as_uint(p.w)] = visible ? 1.0f : 0.0f;
        if (visible) {
            int vp = atomicAdd(&vcnt, 1);
            if (vp < VCAP) { vx[vp] = x; vy[vp] = y; vz[vp] = z; }
        }
    }
    __syncthreads();   // S5

    // P6: tap-parallel splat; (e,tap) tracked incrementally (step +1024 = +20e +44t)
    int nv = vcnt; if (nv > VCAP) nv = VCAP;
    int total3 = nv * 49;
    int e = (int)((unsigned int)tid / 49u);            // one-time exact division
    int tap = tid - e * 49;
    for (int g = tid; g < total3; g += 1024) {
        int r = ((unsigned int)(tap * 37)) >> 8;       // tap/7, exact for 0..48
        int c = tap - r * 7;
        float x = vx[e], y = vy[e], z = vz[e];
        int px = __float2int_rn(x);
        int py = __float2int_rn(y);
        int ii = py - 3 + r, jj = px - 3 + c;
        int li = ii - base_i, lj = jj - base_j;
        if (li >= 0 && li < 32 && lj >= 0 && lj < 32) {
            float dy = y - (float)ii, dx = x - (float)jj;
            float w = 1.0f / (dx * dx + dy * dy + EPSW);
            atomicAdd(&sdep[li * SDS + lj], w * z);
            atomicAdd(&swei[li * SDS + lj], w);
        }
        e += 20; tap += 44;                            // 1024 = 20*49 + 44
        if (tap >= 49) { tap -= 49; e += 1; }
    }
    __syncthreads();   // S6

    // P7: dense coalesced stores (each pixel owned by exactly one tile)
    for (int t = tid; t < 32 * 32; t += 1024) {
        int li = t >> 5, lj = t & 31;
        int g = b * HW + (base_i + li) * WW + (base_j + lj);
        depth[g]  = sdep[li * SDS + lj];
        weight[g] = swei[li * SDS + lj];
    }
}

extern "C" void kernel_launch(void* const* d_in, const int* in_sizes, int n_in,
                              void* d_out, int out_size, void* d_ws, size_t ws_size,
                              hipStream_t stream) {
    const float* pts   = (const float*)d_in[0];   // [B, N, 3]
    const float* thr_p = (const float*)d_in[1];   // scalar

    float* depth  = (float*)d_out;                 // [B*H*W]
    float* weight = depth + NB * HW;               // [B*H*W]
    float* vis    = weight + NB * HW;              // [B*N]

    unsigned char* counts  = (unsigned char*)d_ws;                 // [B][64][256] 128 KB
    unsigned int*  entries = (unsigned int*)(counts + NB * TPB * BPI); // [B][256][64][30] ~15.7 MB

    bin_k<<<NB * BPI, 256, 0, stream>>>(pts, vis, counts, entries);
    splat_k<<<NB * TPB, 1024, 0, stream>>>(counts, entries, pts, thr_p, vis, depth, weight);
}